// Round 1
// 323.753 us; speedup vs baseline: 1.1473x; 1.1473x over previous
//
#include <hip/hip_runtime.h>
#include <hip/hip_bf16.h>

typedef unsigned short bf16_t;  // raw bf16 bits
typedef __attribute__((ext_vector_type(4))) float f32x4;
typedef __attribute__((ext_vector_type(8))) unsigned short us8;

__device__ __forceinline__ float bf2f(bf16_t u) {
  return __uint_as_float(((unsigned int)u) << 16);
}
__device__ __forceinline__ bf16_t f2bf(float f) {
  unsigned int u = __float_as_uint(f);
  return (bf16_t)((u + 0x7FFFu + ((u >> 16) & 1u)) >> 16);  // RNE
}

// Identifier kernel, zero-parameter form (load-bearing: parameterized variant
// broke the harness in rounds 1-5).
__global__ void UnifiedGNN_56521769616171_kernel() {}

// ---------------- setup: degree count / scan / CSR fill ----------------

__global__ void gnn_zero(int* p, int n) {
  int i = blockIdx.x * 256 + threadIdx.x;
  if (i < n) p[i] = 0;
}

__global__ void gnn_count(const int* dst, int* counts, int e, int n) {
  int i = blockIdx.x * 256 + threadIdx.x;
  if (i < e) {
    int d = dst[i];
    if (d >= 0 && d < n) atomicAdd(&counts[d], 1);
  }
}

__global__ void gnn_scan1(const int* counts, int* row_ptr, int* partials, int n) {
  __shared__ int wsum[4];
  int tid = threadIdx.x;
  int base = blockIdx.x * 1024 + tid * 4;
  int a0 = 0, a1 = 0, a2 = 0, a3 = 0;
  if (base + 3 < n) {
    a0 = counts[base]; a1 = counts[base + 1];
    a2 = counts[base + 2]; a3 = counts[base + 3];
  } else if (base < n) {
    a0 = counts[base];
    if (base + 1 < n) a1 = counts[base + 1];
    if (base + 2 < n) a2 = counts[base + 2];
  }
  int s0 = a0, s1 = s0 + a1, s2 = s1 + a2, s3 = s2 + a3;
  int lane = tid & 63;
  int wv = tid >> 6;
  int incl = s3;
  for (int off = 1; off < 64; off <<= 1) {
    int t = __shfl_up(incl, off);
    if (lane >= off) incl += t;
  }
  if (lane == 63) wsum[wv] = incl;
  __syncthreads();
  int woff = 0;
  for (int j = 0; j < 4; j++)
    if (j < wv) woff += wsum[j];
  int excl = woff + incl - s3;
  if (base < n) {
    row_ptr[base] = excl;
    if (base + 1 < n) row_ptr[base + 1] = excl + s0;
    if (base + 2 < n) row_ptr[base + 2] = excl + s1;
    if (base + 3 < n) row_ptr[base + 3] = excl + s2;
  }
  if (tid == 255) partials[blockIdx.x] = wsum[0] + wsum[1] + wsum[2] + wsum[3];
}

__global__ void gnn_scan2(const int* partials, int* offsets, int nb,
                          int* row_ptr, int n, int etot) {
  int l = threadIdx.x;
  int v = 0;
  if (l < nb) v = partials[l];
  int orig = v;
  for (int off = 1; off < 64; off <<= 1) {
    int t = __shfl_up(v, off);
    if (l >= off) v += t;
  }
  offsets[l] = v - orig;
  if (l == 0) row_ptr[n] = etot;
}

__global__ void gnn_scan3(int* row_ptr, const int* offsets, int* cursor,
                          const int* counts, float* dis, int n) {
  int base = blockIdx.x * 1024 + threadIdx.x * 4;
  int off = offsets[blockIdx.x];
  for (int j = 0; j < 4; j++) {
    int i = base + j;
    if (i < n) {
      int rp = row_ptr[i] + off;
      row_ptr[i] = rp;
      cursor[i] = rp;
      dis[i] = rsqrtf((float)counts[i] + 1.0f);  // degree incl. self-loop
    }
  }
}

__global__ void gnn_fill(const int* src, const int* dst, int* cursor,
                         int* csr, int e, int n) {
  int i = blockIdx.x * 256 + threadIdx.x;
  if (i < e) {
    int d = dst[i];
    if (d >= 0 && d < n) {
      int pos = atomicAdd(&cursor[d], 1);
      csr[pos] = src[i];
    }
  }
}

// ---- hi/lo bf16 split of f32 X (conv1 input): hi -> Hi, residual -> Lo ----
__global__ void gnn_x2bf(const float* X, bf16_t* Hi, bf16_t* Lo, long n128) {
  long i = ((long)blockIdx.x * 256 + threadIdx.x) * 8;
  if (i + 7 < n128) {
    float4 a = *(const float4*)(X + i);
    float4 b = *(const float4*)(X + i + 4);
    ushort4 h1, h2, l1, l2;
    h1.x = f2bf(a.x); l1.x = f2bf(a.x - bf2f(h1.x));
    h1.y = f2bf(a.y); l1.y = f2bf(a.y - bf2f(h1.y));
    h1.z = f2bf(a.z); l1.z = f2bf(a.z - bf2f(h1.z));
    h1.w = f2bf(a.w); l1.w = f2bf(a.w - bf2f(h1.w));
    h2.x = f2bf(b.x); l2.x = f2bf(b.x - bf2f(h2.x));
    h2.y = f2bf(b.y); l2.y = f2bf(b.y - bf2f(h2.y));
    h2.z = f2bf(b.z); l2.z = f2bf(b.z - bf2f(h2.z));
    h2.w = f2bf(b.w); l2.w = f2bf(b.w - bf2f(h2.w));
    *(ushort4*)(Hi + i) = h1; *(ushort4*)(Hi + i + 4) = h2;
    *(ushort4*)(Lo + i) = l1; *(ushort4*)(Lo + i + 4) = l2;
  } else {
    for (; i < n128; i++) {
      bf16_t h = f2bf(X[i]);
      Hi[i] = h;
      Lo[i] = f2bf(X[i] - bf2f(h));
    }
  }
}

// ------- MFMA GEMM: A[r][c] = dis[r] * sum_k X[r][k] * W[k][c] -> bf16 -------
// W staged once/block to LDS as Wt[col][k] bf16 with 16B-chunk XOR swizzle
// (chunk kb ^= col&15) so B-frag ds_read_b128 is bank-uniform (T2; without it
// 16 rows x same col-range = 16-way conflict).
// Per wave: 16 rows x 128 cols, 8 acc f32x4, 4 k-steps of mfma 16x16x32 bf16.
// A-frag: lane reads X[row0+(l&15)][ks*32+(l>>4)*8 ..+8] (16B global load).
// C/D layout (m89-verified): col=lane&15, row=(lane>>4)*4+reg.
// Optional Xlo (hi/lo split, conv1): second MFMA per k-step, same acc.
// Inline-asm MFMA: s_nop 2 covers VALU(acc-init)->MFMA SrcC hazard; epilogue
// s_nop 7 pair is operand-tied to accs so reads can't hoist above it.
__global__ __launch_bounds__(256) void gnn_gemm(const bf16_t* X, const bf16_t* Xlo,
    const float* W, const float* dis, bf16_t* A, int n, int ntiles) {
  __shared__ __align__(16) bf16_t Wt[128 * 128];  // 32 KB
  int tid = threadIdx.x;

  // stage W transposed+swizzled: Wt[c][k], chunk(kb)=k>>3 xor'd with c&15
  for (int j = tid; j < 2048; j += 256) {
    int c = j & 127;
    int kb = j >> 7;  // 0..15
    int k0 = kb << 3;
    us8 v;
#pragma unroll
    for (int i = 0; i < 8; i++) v[i] = f2bf(W[(size_t)(k0 + i) * 128 + c]);
    *(us8*)&Wt[c * 128 + ((kb ^ (c & 15)) << 3)] = v;
  }
  __syncthreads();

  int lane = tid & 63;
  int wid = tid >> 6;   // 0..3 (wave id)
  int l15 = lane & 15;
  int lk = lane >> 4;   // 0..3 (k-group)

  for (int t = blockIdx.x; t < ntiles; t += gridDim.x) {
    int rowbase = t * 64 + wid * 16;
    int arow = rowbase + l15;
    int arc = arow < n ? arow : (n - 1);  // clamp: garbage rows are never stored
    const us8* Xr = (const us8*)(X + (size_t)arc * 128);
    const us8* Xl = Xlo ? (const us8*)(Xlo + (size_t)arc * 128) : (const us8*)0;

    f32x4 acc[8];
#pragma unroll
    for (int c = 0; c < 8; c++) {
      acc[c][0] = 0.0f; acc[c][1] = 0.0f; acc[c][2] = 0.0f; acc[c][3] = 0.0f;
    }

#pragma unroll
    for (int ks = 0; ks < 4; ks++) {
      int kb = ks * 4 + lk;  // 16B chunk index in k
      us8 ah = Xr[kb];
#pragma unroll
      for (int c = 0; c < 8; c++) {
        int col = c * 16 + l15;
        us8 bf = *(const us8*)&Wt[col * 128 + ((kb ^ l15) << 3)];
        asm volatile("s_nop 2\n\tv_mfma_f32_16x16x32_bf16 %0, %1, %2, %0"
                     : "+v"(acc[c]) : "v"(ah), "v"(bf));
      }
      if (Xlo) {
        us8 al = Xl[kb];
#pragma unroll
        for (int c = 0; c < 8; c++) {
          int col = c * 16 + l15;
          us8 bf = *(const us8*)&Wt[col * 128 + ((kb ^ l15) << 3)];
          asm volatile("s_nop 2\n\tv_mfma_f32_16x16x32_bf16 %0, %1, %2, %0"
                       : "+v"(acc[c]) : "v"(al), "v"(bf));
        }
      }
    }
    // MFMA->VALU read hazard drain; operand-tied so acc reads can't hoist.
    asm volatile("s_nop 7\n\ts_nop 7"
                 : "+v"(acc[0]), "+v"(acc[1]), "+v"(acc[2]), "+v"(acc[3]),
                   "+v"(acc[4]), "+v"(acc[5]), "+v"(acc[6]), "+v"(acc[7]));

#pragma unroll
    for (int j = 0; j < 4; j++) {
      int row = rowbase + lk * 4 + j;
      if (row < n) {
        float dd = dis[row];
#pragma unroll
        for (int c = 0; c < 8; c++) {
          A[(size_t)row * 128 + c * 16 + l15] = f2bf(acc[c][j] * dd);
        }
      }
    }
  }
}

// --- fused aggregation (+ optional residual+LN+relu) ---
// A holds dis[s]*h[s] (bf16). h_agg[d] = dis[d]*(sum_{s in N(d)} A[s] + A[d]) + bias.
// do_ln: v = h_agg + ori; LN(v)*w+b; relu; write bf16 to Bout.
// else: write f32 h_agg to Fout.

__global__ __launch_bounds__(256) void gnn_aggln(const bf16_t* A,
    const float* dis, const int* row_ptr, const int* csr, const float* bias,
    const float* ori, const float* lnw, const float* lnb,
    bf16_t* Bout, float* Fout, int n, int do_ln) {
  int row = blockIdx.x * 4 + (threadIdx.x >> 6);
  if (row >= n) return;
  int lane = threadIdx.x & 63;
  int e0 = row_ptr[row];
  int e1 = row_ptr[row + 1];
  const ushort2* Av = (const ushort2*)A;
  float ax0 = 0.f, ay0 = 0.f, ax1 = 0.f, ay1 = 0.f;
  float ax2 = 0.f, ay2 = 0.f, ax3 = 0.f, ay3 = 0.f;
  int e = e0;
  for (; e + 3 < e1; e += 4) {  // 4-way unroll: 4 gathers in flight
    int s0 = csr[e], s1 = csr[e + 1], s2 = csr[e + 2], s3 = csr[e + 3];
    ushort2 v0 = Av[(size_t)s0 * 64 + lane];
    ushort2 v1 = Av[(size_t)s1 * 64 + lane];
    ushort2 v2 = Av[(size_t)s2 * 64 + lane];
    ushort2 v3 = Av[(size_t)s3 * 64 + lane];
    ax0 += bf2f(v0.x); ay0 += bf2f(v0.y);
    ax1 += bf2f(v1.x); ay1 += bf2f(v1.y);
    ax2 += bf2f(v2.x); ay2 += bf2f(v2.y);
    ax3 += bf2f(v3.x); ay3 += bf2f(v3.y);
  }
  for (; e < e1; ++e) {
    int s = csr[e];
    ushort2 v = Av[(size_t)s * 64 + lane];
    ax0 += bf2f(v.x); ay0 += bf2f(v.y);
  }
  ushort2 sv = Av[(size_t)row * 64 + lane];  // self-loop term
  float ax = ax0 + ax1 + ax2 + ax3 + bf2f(sv.x);
  float ay = ay0 + ay1 + ay2 + ay3 + bf2f(sv.y);
  float dd = dis[row];
  float2 bb = ((const float2*)bias)[lane];
  float hx = dd * ax + bb.x;
  float hy = dd * ay + bb.y;

  if (do_ln) {
    float2 o2 = ((const float2*)ori)[(size_t)row * 64 + lane];
    float vx = hx + o2.x;
    float vy = hy + o2.y;
    float s = vx + vy;
    float sq = vx * vx + vy * vy;
    for (int off = 32; off >= 1; off >>= 1) {
      s += __shfl_xor(s, off);
      sq += __shfl_xor(sq, off);
    }
    float mu = s * (1.0f / 128.0f);
    float var = sq * (1.0f / 128.0f) - mu * mu;
    float inv = rsqrtf(var + 1e-5f);
    float2 w2 = ((const float2*)lnw)[lane];
    float2 b2 = ((const float2*)lnb)[lane];
    float y0 = (vx - mu) * inv * w2.x + b2.x;
    float y1 = (vy - mu) * inv * w2.y + b2.y;
    if (y0 < 0.0f) y0 = 0.0f;
    if (y1 < 0.0f) y1 = 0.0f;
    ushort2 o;
    o.x = f2bf(y0);
    o.y = f2bf(y1);
    ((ushort2*)Bout)[(size_t)row * 64 + lane] = o;
  } else {
    ((float2*)Fout)[(size_t)row * 64 + lane] = make_float2(hx, hy);
  }
}

// ---------------- driver ----------------

extern "C" void kernel_launch(void* const* d_in, const int* in_sizes, int n_in,
                              void* d_out, int out_size, void* d_ws, size_t ws_size,
                              hipStream_t stream) {
  UnifiedGNN_56521769616171_kernel<<<1, 64, 0, stream>>>();

  // input classification by size (identity under documented dict order)
  int nI = (n_in > 0 && n_in <= 16) ? n_in : 11;
  long best = -1;
  int iFeat = 0;
  for (int i = 0; i < nI; i++)
    if ((long)in_sizes[i] > best) { best = in_sizes[i]; iFeat = i; }
  int iW[2], iV[6], iE[2];
  int nW = 0, nV = 0, nE = 0;
  for (int i = 0; i < nI; i++) {
    if (i == iFeat) continue;
    int s = in_sizes[i];
    if (s == 128 * 128) { if (nW < 2) iW[nW++] = i; }
    else if (s == 128)  { if (nV < 6) iV[nV++] = i; }
    else                { if (nE < 2) iE[nE++] = i; }
  }
  int aFeat = 0, aEs = 1, aEd = 2, aW1 = 3, aB1 = 4, aW2 = 5, aB2 = 6,
      aL1w = 7, aL1b = 8, aL2w = 9, aL2b = 10;
  if (nW == 2 && nV == 6 && nE == 2) {
    aFeat = iFeat;
    aEs = iE[0]; aEd = iE[1];
    aW1 = iW[0]; aW2 = iW[1];
    aB1 = iV[0]; aB2 = iV[1];
    aL1w = iV[2]; aL1b = iV[3]; aL2w = iV[4]; aL2b = iV[5];
  }

  int N = 50000;
  int E = 600000;
  if (in_sizes[aFeat] > 0 && (in_sizes[aFeat] % 128) == 0) N = in_sizes[aFeat] / 128;
  if (in_sizes[aEs] > 0) E = in_sizes[aEs];

  const float* in_feat = (const float*)d_in[aFeat];
  const int*   esrc    = (const int*)d_in[aEs];
  const int*   edst    = (const int*)d_in[aEd];
  const float* W1      = (const float*)d_in[aW1];
  const float* b1      = (const float*)d_in[aB1];
  const float* W2      = (const float*)d_in[aW2];
  const float* b2      = (const float*)d_in[aB2];
  const float* ln1w    = (const float*)d_in[aL1w];
  const float* ln1b    = (const float*)d_in[aL1b];
  const float* ln2w    = (const float*)d_in[aL2w];
  const float* ln2b    = (const float*)d_in[aL2b];

  // workspace carve (~41.4 MB; ws_size = 256 MiB, confirmed by harness poison
  // fills: WRITE_SIZE=262144 KB per fillBufferAligned dispatch)
  char* base = (char*)d_ws;
  size_t off = 0;
  int* counts = (int*)(base + off);   off += ((size_t)N * 4 + 255) & ~(size_t)255;
  int* row_ptr = (int*)(base + off);  off += ((size_t)(N + 1) * 4 + 255) & ~(size_t)255;
  int* cursor = (int*)(base + off);   off += ((size_t)N * 4 + 255) & ~(size_t)255;
  int* partials = (int*)(base + off); off += 256;
  int* offsets = (int*)(base + off);  off += 256;
  float* dis = (float*)(base + off);  off += ((size_t)N * 4 + 255) & ~(size_t)255;
  int* csr = (int*)(base + off);      off += ((size_t)E * 4 + 255) & ~(size_t)255;
  bf16_t* A = (bf16_t*)(base + off);  off += ((size_t)N * 256 + 255) & ~(size_t)255;  // gemm out (pre-scaled)
  bf16_t* B = (bf16_t*)(base + off);  off += ((size_t)N * 256 + 255) & ~(size_t)255;  // LN out / X-hi
  bf16_t* XL = (bf16_t*)(base + off); off += ((size_t)N * 256 + 255) & ~(size_t)255;  // X-lo (conv1 split)

  int nb = (N + 1023) / 1024;
  int gN = (N + 255) / 256;
  int gE = (E + 255) / 256;
  long n128 = (long)N * 128;
  int cg = (int)((n128 + 2047) / 2048);
  int nt64 = (N + 63) / 64;
  int row_grid = (N + 3) / 4;

  gnn_zero<<<gN, 256, 0, stream>>>(counts, N);
  gnn_count<<<gE, 256, 0, stream>>>(edst, counts, E, N);
  gnn_scan1<<<nb, 256, 0, stream>>>(counts, row_ptr, partials, N);
  gnn_scan2<<<1, 64, 0, stream>>>(partials, offsets, nb, row_ptr, N, E);
  gnn_scan3<<<nb, 256, 0, stream>>>(row_ptr, offsets, cursor, counts, dis, N);
  gnn_fill<<<gE, 256, 0, stream>>>(esrc, edst, cursor, csr, E, N);

  // hi/lo bf16 split of in_feat: hi -> B, lo -> XL (keeps conv1 X at f32 fidelity)
  gnn_x2bf<<<cg, 256, 0, stream>>>(in_feat, B, XL, n128);

  // conv1 + LN1(+res,relu):  A = dis*(in_feat@W1);  B = relu(LN1(agg(A)+b1 + ori))
  gnn_gemm<<<nt64, 256, 0, stream>>>(B, XL, W1, dis, A, N, nt64);
  gnn_aggln<<<row_grid, 256, 0, stream>>>(A, dis, row_ptr, csr, b1, in_feat,
                                          ln1w, ln1b, B, (float*)nullptr, N, 1);

  // conv2 + LN2(+res,relu)
  gnn_gemm<<<nt64, 256, 0, stream>>>(B, (const bf16_t*)nullptr, W2, dis, A, N, nt64);
  gnn_aggln<<<row_grid, 256, 0, stream>>>(A, dis, row_ptr, csr, b2, in_feat,
                                          ln2w, ln2b, B, (float*)nullptr, N, 1);

  // conv3 -> final f32 output
  gnn_gemm<<<nt64, 256, 0, stream>>>(B, (const bf16_t*)nullptr, W2, dis, A, N, nt64);
  gnn_aggln<<<row_grid, 256, 0, stream>>>(A, dis, row_ptr, csr, b2,
                                          (const float*)nullptr, (const float*)nullptr,
                                          (const float*)nullptr, (bf16_t*)nullptr,
                                          (float*)d_out, N, 0);
}

// Round 2
// 284.691 us; speedup vs baseline: 1.3047x; 1.1372x over previous
//
#include <hip/hip_runtime.h>
#include <hip/hip_bf16.h>

typedef unsigned short bf16_t;  // raw bf16 bits
typedef __attribute__((ext_vector_type(4))) float f32x4;
typedef __attribute__((ext_vector_type(8))) unsigned short us8;

__device__ __forceinline__ float bf2f(bf16_t u) {
  return __uint_as_float(((unsigned int)u) << 16);
}
__device__ __forceinline__ bf16_t f2bf(float f) {
  unsigned int u = __float_as_uint(f);
  return (bf16_t)((u + 0x7FFFu + ((u >> 16) & 1u)) >> 16);  // RNE
}

// Identifier kernel, zero-parameter form (load-bearing: parameterized variant
// broke the harness in rounds 1-5).
__global__ void UnifiedGNN_56521769616171_kernel() {}

// ---------------- setup: degree count / scan / CSR fill ----------------

__global__ void gnn_zero(int* p, int n) {
  int i = blockIdx.x * 256 + threadIdx.x;
  if (i < n) p[i] = 0;
}

__global__ void gnn_count(const int* dst, int* counts, int e, int n) {
  int i = blockIdx.x * 256 + threadIdx.x;
  if (i < e) {
    int d = dst[i];
    if (d >= 0 && d < n) atomicAdd(&counts[d], 1);
  }
}

__global__ void gnn_scan1(const int* counts, int* row_ptr, int* partials, int n) {
  __shared__ int wsum[4];
  int tid = threadIdx.x;
  int base = blockIdx.x * 1024 + tid * 4;
  int a0 = 0, a1 = 0, a2 = 0, a3 = 0;
  if (base + 3 < n) {
    a0 = counts[base]; a1 = counts[base + 1];
    a2 = counts[base + 2]; a3 = counts[base + 3];
  } else if (base < n) {
    a0 = counts[base];
    if (base + 1 < n) a1 = counts[base + 1];
    if (base + 2 < n) a2 = counts[base + 2];
  }
  int s0 = a0, s1 = s0 + a1, s2 = s1 + a2, s3 = s2 + a3;
  int lane = tid & 63;
  int wv = tid >> 6;
  int incl = s3;
  for (int off = 1; off < 64; off <<= 1) {
    int t = __shfl_up(incl, off);
    if (lane >= off) incl += t;
  }
  if (lane == 63) wsum[wv] = incl;
  __syncthreads();
  int woff = 0;
  for (int j = 0; j < 4; j++)
    if (j < wv) woff += wsum[j];
  int excl = woff + incl - s3;
  if (base < n) {
    row_ptr[base] = excl;
    if (base + 1 < n) row_ptr[base + 1] = excl + s0;
    if (base + 2 < n) row_ptr[base + 2] = excl + s1;
    if (base + 3 < n) row_ptr[base + 3] = excl + s2;
  }
  if (tid == 255) partials[blockIdx.x] = wsum[0] + wsum[1] + wsum[2] + wsum[3];
}

__global__ void gnn_scan2(const int* partials, int* offsets, int nb,
                          int* row_ptr, int n, int etot) {
  int l = threadIdx.x;
  int v = 0;
  if (l < nb) v = partials[l];
  int orig = v;
  for (int off = 1; off < 64; off <<= 1) {
    int t = __shfl_up(v, off);
    if (l >= off) v += t;
  }
  offsets[l] = v - orig;
  if (l == 0) row_ptr[n] = etot;
}

__global__ void gnn_scan3(int* row_ptr, const int* offsets, int* cursor,
                          const int* counts, float* dis, int n) {
  int base = blockIdx.x * 1024 + threadIdx.x * 4;
  int off = offsets[blockIdx.x];
  for (int j = 0; j < 4; j++) {
    int i = base + j;
    if (i < n) {
      int rp = row_ptr[i] + off;
      row_ptr[i] = rp;
      cursor[i] = rp;
      dis[i] = rsqrtf((float)counts[i] + 1.0f);  // degree incl. self-loop
    }
  }
}

__global__ void gnn_fill(const int* src, const int* dst, int* cursor,
                         int* csr, int e, int n) {
  int i = blockIdx.x * 256 + threadIdx.x;
  if (i < e) {
    int d = dst[i];
    if (d >= 0 && d < n) {
      int pos = atomicAdd(&cursor[d], 1);
      csr[pos] = src[i];
    }
  }
}

// ------- MFMA GEMM: A[r][c] = dis[r] * sum_k X[r][k] * W[k][c] -> bf16 -------
// W staged once/block to LDS as Wt[col][k] bf16 with 16B-chunk XOR swizzle
// (chunk kb ^= col&15) so B-frag ds_read_b128 is bank-uniform (T2; without it
// 16 rows x same col-range = 16-way conflict).
// Per wave: 16 rows x 128 cols, 8 acc f32x4, 4 k-steps of mfma 16x16x32 bf16.
// A-frag: lane reads X[row0+(l&15)][ks*32+(l>>4)*8 ..+8].
// C/D layout (m89-verified): col=lane&15, row=(lane>>4)*4+reg.
// xfmt=0: X is f32; hi/lo bf16 split computed in-register (2 MFMAs/k-step,
// keeps conv1 at ~f32 fidelity; same global bytes as bf16 hi+lo).
// xfmt=1: X is bf16 (1 MFMA/k-step).
// Inline-asm MFMA: s_nop 2 covers VALU(acc-init)->MFMA SrcC hazard; epilogue
// s_nop 7 pair is operand-tied to accs so reads can't hoist above it.
__global__ __launch_bounds__(256) void gnn_gemm(const void* Xv,
    const float* W, const float* dis, bf16_t* A, int n, int ntiles, int xfmt) {
  __shared__ __align__(16) bf16_t Wt[128 * 128];  // 32 KB
  int tid = threadIdx.x;

  // stage W transposed+swizzled: Wt[c][k], chunk(kb)=k>>3 xor'd with c&15
  for (int j = tid; j < 2048; j += 256) {
    int c = j & 127;
    int kb = j >> 7;  // 0..15
    int k0 = kb << 3;
    us8 v;
#pragma unroll
    for (int i = 0; i < 8; i++) v[i] = f2bf(W[(size_t)(k0 + i) * 128 + c]);
    *(us8*)&Wt[c * 128 + ((kb ^ (c & 15)) << 3)] = v;
  }
  __syncthreads();

  int lane = tid & 63;
  int wid = tid >> 6;   // 0..3 (wave id)
  int l15 = lane & 15;
  int lk = lane >> 4;   // 0..3 (k-group)
  const bf16_t* Xb = (const bf16_t*)Xv;
  const float* Xf = (const float*)Xv;

  for (int t = blockIdx.x; t < ntiles; t += gridDim.x) {
    int rowbase = t * 64 + wid * 16;
    int arow = rowbase + l15;
    int arc = arow < n ? arow : (n - 1);  // clamp: garbage rows are never stored

    f32x4 acc[8];
#pragma unroll
    for (int c = 0; c < 8; c++) {
      acc[c][0] = 0.0f; acc[c][1] = 0.0f; acc[c][2] = 0.0f; acc[c][3] = 0.0f;
    }

#pragma unroll
    for (int ks = 0; ks < 4; ks++) {
      int kb = ks * 4 + lk;  // 16B chunk index in k
      us8 ah, al;
      if (xfmt == 0) {
        float4 a0 = *(const float4*)(Xf + (size_t)arc * 128 + kb * 8);
        float4 a1 = *(const float4*)(Xf + (size_t)arc * 128 + kb * 8 + 4);
        ah[0] = f2bf(a0.x); al[0] = f2bf(a0.x - bf2f(ah[0]));
        ah[1] = f2bf(a0.y); al[1] = f2bf(a0.y - bf2f(ah[1]));
        ah[2] = f2bf(a0.z); al[2] = f2bf(a0.z - bf2f(ah[2]));
        ah[3] = f2bf(a0.w); al[3] = f2bf(a0.w - bf2f(ah[3]));
        ah[4] = f2bf(a1.x); al[4] = f2bf(a1.x - bf2f(ah[4]));
        ah[5] = f2bf(a1.y); al[5] = f2bf(a1.y - bf2f(ah[5]));
        ah[6] = f2bf(a1.z); al[6] = f2bf(a1.z - bf2f(ah[6]));
        ah[7] = f2bf(a1.w); al[7] = f2bf(a1.w - bf2f(ah[7]));
      } else {
        ah = *(const us8*)(Xb + (size_t)arc * 128 + kb * 8);
      }
#pragma unroll
      for (int c = 0; c < 8; c++) {
        int col = c * 16 + l15;
        us8 bf = *(const us8*)&Wt[col * 128 + ((kb ^ l15) << 3)];
        asm volatile("s_nop 2\n\tv_mfma_f32_16x16x32_bf16 %0, %1, %2, %0"
                     : "+v"(acc[c]) : "v"(ah), "v"(bf));
      }
      if (xfmt == 0) {
#pragma unroll
        for (int c = 0; c < 8; c++) {
          int col = c * 16 + l15;
          us8 bf = *(const us8*)&Wt[col * 128 + ((kb ^ l15) << 3)];
          asm volatile("s_nop 2\n\tv_mfma_f32_16x16x32_bf16 %0, %1, %2, %0"
                       : "+v"(acc[c]) : "v"(al), "v"(bf));
        }
      }
    }
    // MFMA->VALU read hazard drain; operand-tied so acc reads can't hoist.
    asm volatile("s_nop 7\n\ts_nop 7"
                 : "+v"(acc[0]), "+v"(acc[1]), "+v"(acc[2]), "+v"(acc[3]),
                   "+v"(acc[4]), "+v"(acc[5]), "+v"(acc[6]), "+v"(acc[7]));

#pragma unroll
    for (int j = 0; j < 4; j++) {
      int row = rowbase + lk * 4 + j;
      if (row < n) {
        float dd = dis[row];
#pragma unroll
        for (int c = 0; c < 8; c++) {
          A[(size_t)row * 128 + c * 16 + l15] = f2bf(acc[c][j] * dd);
        }
      }
    }
  }
}

// --- fused aggregation (+ optional residual+LN+relu) ---
// A holds dis[s]*h[s] (bf16). h_agg[d] = dis[d]*(sum_{s in N(d)} A[s] + A[d]) + bias.
// Layout: 16 lanes per row (us8 = 16B per lane), 4 rows per wave, 16 rows/block.
// Edge indices fetched cooperatively 16-at-a-time, distributed intra-group via
// __shfl (source lanes always in same group -> never reads inactive lanes).
// Up to 16 independent 16B gathers in flight per group (latency hiding).
// do_ln: v = h_agg + ori; LN(v)*w+b; relu; write bf16 to Bout.
// else: write f32 h_agg to Fout.
__global__ __launch_bounds__(256) void gnn_aggln(const bf16_t* A,
    const float* dis, const int* row_ptr, const int* csr, const float* bias,
    const float* ori, const float* lnw, const float* lnb,
    bf16_t* Bout, float* Fout, int n, int do_ln) {
  int wid = threadIdx.x >> 6;
  int lane = threadIdx.x & 63;
  int g = lane >> 4;    // group 0..3 within wave
  int l16 = lane & 15;  // lane within group
  int row = blockIdx.x * 16 + wid * 4 + g;
  bool active = row < n;
  int rc = active ? row : (n - 1);
  int e0 = row_ptr[rc];
  int e1 = active ? row_ptr[rc + 1] : e0;
  const us8* Av8 = (const us8*)A;

  float ax[8];
#pragma unroll
  for (int i = 0; i < 8; i++) ax[i] = 0.0f;

  for (int e = e0; e < e1; e += 16) {
    int nv = e1 - e;
    if (nv > 16) nv = 16;
    int sv = csr[e + (l16 < nv ? l16 : 0)];  // clamped: no OOB past e1
#pragma unroll
    for (int j = 0; j < 16; j++) {
      if (j >= nv) break;
      int s = __shfl(sv, (g << 4) + j);
      us8 v = Av8[(size_t)s * 16 + l16];
#pragma unroll
      for (int i = 0; i < 8; i++) ax[i] += bf2f(v[i]);
    }
  }
  // self-loop term
  us8 sv8 = Av8[(size_t)rc * 16 + l16];
#pragma unroll
  for (int i = 0; i < 8; i++) ax[i] += bf2f(sv8[i]);

  float dd = dis[rc];
  float4 bb0 = *(const float4*)(bias + l16 * 8);
  float4 bb1 = *(const float4*)(bias + l16 * 8 + 4);
  float h[8];
  h[0] = dd * ax[0] + bb0.x; h[1] = dd * ax[1] + bb0.y;
  h[2] = dd * ax[2] + bb0.z; h[3] = dd * ax[3] + bb0.w;
  h[4] = dd * ax[4] + bb1.x; h[5] = dd * ax[5] + bb1.y;
  h[6] = dd * ax[6] + bb1.z; h[7] = dd * ax[7] + bb1.w;

  if (do_ln) {
    float4 o0 = *(const float4*)(ori + (size_t)rc * 128 + l16 * 8);
    float4 o1 = *(const float4*)(ori + (size_t)rc * 128 + l16 * 8 + 4);
    float v[8];
    v[0] = h[0] + o0.x; v[1] = h[1] + o0.y; v[2] = h[2] + o0.z; v[3] = h[3] + o0.w;
    v[4] = h[4] + o1.x; v[5] = h[5] + o1.y; v[6] = h[6] + o1.z; v[7] = h[7] + o1.w;
    float s = 0.0f, sq = 0.0f;
#pragma unroll
    for (int i = 0; i < 8; i++) { s += v[i]; sq += v[i] * v[i]; }
    for (int off = 8; off >= 1; off >>= 1) {  // intra-group (16-lane) reduce
      s += __shfl_xor(s, off);
      sq += __shfl_xor(sq, off);
    }
    float mu = s * (1.0f / 128.0f);
    float var = sq * (1.0f / 128.0f) - mu * mu;
    float inv = rsqrtf(var + 1e-5f);
    float4 w0 = *(const float4*)(lnw + l16 * 8);
    float4 w1 = *(const float4*)(lnw + l16 * 8 + 4);
    float4 c0 = *(const float4*)(lnb + l16 * 8);
    float4 c1 = *(const float4*)(lnb + l16 * 8 + 4);
    float wv[8] = {w0.x, w0.y, w0.z, w0.w, w1.x, w1.y, w1.z, w1.w};
    float cv[8] = {c0.x, c0.y, c0.z, c0.w, c1.x, c1.y, c1.z, c1.w};
    us8 o8;
#pragma unroll
    for (int i = 0; i < 8; i++) {
      float y = (v[i] - mu) * inv * wv[i] + cv[i];
      if (y < 0.0f) y = 0.0f;
      o8[i] = f2bf(y);
    }
    if (active) *(us8*)(Bout + (size_t)rc * 128 + l16 * 8) = o8;
  } else {
    if (active) {
      float4 f0 = make_float4(h[0], h[1], h[2], h[3]);
      float4 f1 = make_float4(h[4], h[5], h[6], h[7]);
      *(float4*)(Fout + (size_t)rc * 128 + l16 * 8) = f0;
      *(float4*)(Fout + (size_t)rc * 128 + l16 * 8 + 4) = f1;
    }
  }
}

// ---------------- driver ----------------

extern "C" void kernel_launch(void* const* d_in, const int* in_sizes, int n_in,
                              void* d_out, int out_size, void* d_ws, size_t ws_size,
                              hipStream_t stream) {
  UnifiedGNN_56521769616171_kernel<<<1, 64, 0, stream>>>();

  // input classification by size (identity under documented dict order)
  int nI = (n_in > 0 && n_in <= 16) ? n_in : 11;
  long best = -1;
  int iFeat = 0;
  for (int i = 0; i < nI; i++)
    if ((long)in_sizes[i] > best) { best = in_sizes[i]; iFeat = i; }
  int iW[2], iV[6], iE[2];
  int nW = 0, nV = 0, nE = 0;
  for (int i = 0; i < nI; i++) {
    if (i == iFeat) continue;
    int s = in_sizes[i];
    if (s == 128 * 128) { if (nW < 2) iW[nW++] = i; }
    else if (s == 128)  { if (nV < 6) iV[nV++] = i; }
    else                { if (nE < 2) iE[nE++] = i; }
  }
  int aFeat = 0, aEs = 1, aEd = 2, aW1 = 3, aB1 = 4, aW2 = 5, aB2 = 6,
      aL1w = 7, aL1b = 8, aL2w = 9, aL2b = 10;
  if (nW == 2 && nV == 6 && nE == 2) {
    aFeat = iFeat;
    aEs = iE[0]; aEd = iE[1];
    aW1 = iW[0]; aW2 = iW[1];
    aB1 = iV[0]; aB2 = iV[1];
    aL1w = iV[2]; aL1b = iV[3]; aL2w = iV[4]; aL2b = iV[5];
  }

  int N = 50000;
  int E = 600000;
  if (in_sizes[aFeat] > 0 && (in_sizes[aFeat] % 128) == 0) N = in_sizes[aFeat] / 128;
  if (in_sizes[aEs] > 0) E = in_sizes[aEs];

  const float* in_feat = (const float*)d_in[aFeat];
  const int*   esrc    = (const int*)d_in[aEs];
  const int*   edst    = (const int*)d_in[aEd];
  const float* W1      = (const float*)d_in[aW1];
  const float* b1      = (const float*)d_in[aB1];
  const float* W2      = (const float*)d_in[aW2];
  const float* b2      = (const float*)d_in[aB2];
  const float* ln1w    = (const float*)d_in[aL1w];
  const float* ln1b    = (const float*)d_in[aL1b];
  const float* ln2w    = (const float*)d_in[aL2w];
  const float* ln2b    = (const float*)d_in[aL2b];

  // workspace carve (~28.6 MB; ws_size = 256 MiB, confirmed by harness poison
  // fills: WRITE_SIZE=262144 KB per fillBufferAligned dispatch)
  char* base = (char*)d_ws;
  size_t off = 0;
  int* counts = (int*)(base + off);   off += ((size_t)N * 4 + 255) & ~(size_t)255;
  int* row_ptr = (int*)(base + off);  off += ((size_t)(N + 1) * 4 + 255) & ~(size_t)255;
  int* cursor = (int*)(base + off);   off += ((size_t)N * 4 + 255) & ~(size_t)255;
  int* partials = (int*)(base + off); off += 256;
  int* offsets = (int*)(base + off);  off += 256;
  float* dis = (float*)(base + off);  off += ((size_t)N * 4 + 255) & ~(size_t)255;
  int* csr = (int*)(base + off);      off += ((size_t)E * 4 + 255) & ~(size_t)255;
  bf16_t* A = (bf16_t*)(base + off);  off += ((size_t)N * 256 + 255) & ~(size_t)255;  // gemm out (pre-scaled)
  bf16_t* B = (bf16_t*)(base + off);  off += ((size_t)N * 256 + 255) & ~(size_t)255;  // LN out

  int nb = (N + 1023) / 1024;
  int gN = (N + 255) / 256;
  int gE = (E + 255) / 256;
  int nt64 = (N + 63) / 64;
  int agg_grid = (N + 15) / 16;

  gnn_zero<<<gN, 256, 0, stream>>>(counts, N);
  gnn_count<<<gE, 256, 0, stream>>>(edst, counts, E, N);
  gnn_scan1<<<nb, 256, 0, stream>>>(counts, row_ptr, partials, N);
  gnn_scan2<<<1, 64, 0, stream>>>(partials, offsets, nb, row_ptr, N, E);
  gnn_scan3<<<nb, 256, 0, stream>>>(row_ptr, offsets, cursor, counts, dis, N);
  gnn_fill<<<gE, 256, 0, stream>>>(esrc, edst, cursor, csr, E, N);

  // conv1 + LN1(+res,relu):  A = dis*(in_feat@W1);  B = relu(LN1(agg(A)+b1 + ori))
  // conv1 GEMM consumes f32 X directly (in-register hi/lo split, xfmt=0)
  gnn_gemm<<<nt64, 256, 0, stream>>>(in_feat, W1, dis, A, N, nt64, 0);
  gnn_aggln<<<agg_grid, 256, 0, stream>>>(A, dis, row_ptr, csr, b1, in_feat,
                                          ln1w, ln1b, B, (float*)nullptr, N, 1);

  // conv2 + LN2(+res,relu)
  gnn_gemm<<<nt64, 256, 0, stream>>>(B, W2, dis, A, N, nt64, 1);
  gnn_aggln<<<agg_grid, 256, 0, stream>>>(A, dis, row_ptr, csr, b2, in_feat,
                                          ln2w, ln2b, B, (float*)nullptr, N, 1);

  // conv3 -> final f32 output
  gnn_gemm<<<nt64, 256, 0, stream>>>(B, W2, dis, A, N, nt64, 1);
  gnn_aggln<<<agg_grid, 256, 0, stream>>>(A, dis, row_ptr, csr, b2,
                                          (const float*)nullptr, (const float*)nullptr,
                                          (const float*)nullptr, (bf16_t*)nullptr,
                                          (float*)d_out, N, 0);
}